// Round 2
// baseline (417.586 us; speedup 1.0000x reference)
//
#include <hip/hip_runtime.h>
#include <math.h>

#define H_ 192
#define W_ 192
#define HW_ (H_*W_)      // 36864
#define B_ 2
#define C_ 64
#define NPIX_ (B_*HW_)   // 73728
#define EPSV 1e-5f

// ---------------------------------------------------------------------------
// Fold: w1t[c][o] = w1[o][c];  wk[k][c][p] = sum_o w2[p,o]*dw[o,c,k];
//       beff[p]  = sum_o w2[p,o]*db[o] + b2[p].  Also zero sums2[128].
// ---------------------------------------------------------------------------
__global__ void k_fold(const float* __restrict__ w1, const float* __restrict__ w2,
                       const float* __restrict__ dw, const float* __restrict__ db,
                       const float* __restrict__ b2,
                       float* __restrict__ w1t, float* __restrict__ wk,
                       float* __restrict__ beff, float* __restrict__ sums2)
{
    int tid = blockIdx.x * 256 + threadIdx.x;   // 0..36863
    if (tid < 9 * 64 * 64) {
        int k = tid >> 12;
        int r = tid & 4095;
        int c = r >> 6;
        int p = r & 63;
        float acc = 0.f;
        #pragma unroll 8
        for (int o = 0; o < 64; ++o)
            acc = fmaf(w2[p * 64 + o], dw[(o * 64 + c) * 9 + k], acc);
        wk[tid] = acc;
    }
    if (tid < 4096) {
        int c = tid >> 6, o = tid & 63;
        w1t[c * 64 + o] = w1[o * 64 + c];
    }
    if (tid < 128) sums2[tid] = 0.f;
    if (tid < 64) {
        float acc = b2[tid];
        #pragma unroll 8
        for (int o = 0; o < 64; ++o) acc = fmaf(w2[tid * 64 + o], db[o], acc);
        beff[tid] = acc;
    }
}

// ---------------------------------------------------------------------------
// conv1x1 #1: y[b,o,hw] = sum_c x[b,c,hw]*w1t[c][o] + b1[o]  (raw, pre-BN)
// ---------------------------------------------------------------------------
__global__ __launch_bounds__(256) void k_conv1x1(const float* __restrict__ x,
        const float* __restrict__ w1t, const float* __restrict__ b1,
        float* __restrict__ y)
{
    __shared__ __align__(16) float xs[64][64];   // [c][p]
    __shared__ __align__(16) float wsh[64][64];  // [c][o]
    int t = threadIdx.x;
    int base = blockIdx.x * 64;
    int b = base / HW_;
    int hw0 = base % HW_;

    #pragma unroll
    for (int i = 0; i < 16; ++i) {
        int e = t + i * 256;
        ((float*)wsh)[e] = w1t[e];
    }
    int p = t & 63, cg = t >> 6;
    #pragma unroll
    for (int i = 0; i < 16; ++i) {
        int c = cg * 16 + i;
        xs[c][p] = x[(b * 64 + c) * HW_ + hw0 + p];
    }
    __syncthreads();

    int l = t & 63, wv = t >> 6;
    int pg = l & 15;
    int og = wv * 4 + (l >> 4);
    float acc[4][4];
    #pragma unroll
    for (int i = 0; i < 4; ++i)
        #pragma unroll
        for (int j = 0; j < 4; ++j) acc[i][j] = 0.f;

    #pragma unroll 8
    for (int c = 0; c < 64; ++c) {
        float va[4], wa[4];
        *(float4*)va = *(const float4*)&xs[c][pg * 4];
        *(float4*)wa = *(const float4*)&wsh[c][og * 4];
        #pragma unroll
        for (int i = 0; i < 4; ++i)
            #pragma unroll
            for (int j = 0; j < 4; ++j)
                acc[i][j] = fmaf(va[i], wa[j], acc[i][j]);
    }

    #pragma unroll
    for (int j = 0; j < 4; ++j) {
        int oc = og * 4 + j;
        float bias = b1[oc];
        float4 o4 = make_float4(acc[0][j] + bias, acc[1][j] + bias,
                                acc[2][j] + bias, acc[3][j] + bias);
        *(float4*)&y[(b * 64 + oc) * HW_ + hw0 + pg * 4] = o4;
    }
}

// ---------------------------------------------------------------------------
// BN1 stats over raw conv output: writes scale, shift
// ---------------------------------------------------------------------------
__global__ void k_stats(const float* __restrict__ y, const float* __restrict__ g,
                        const float* __restrict__ be, float* __restrict__ scsh)
{
    int c = blockIdx.x;
    int t = threadIdx.x;
    float s = 0.f, sq = 0.f;
    for (int b = 0; b < B_; ++b) {
        const float4* p4 = (const float4*)&y[(b * 64 + c) * HW_];
        for (int i = t; i < HW_ / 4; i += 256) {
            float4 v = p4[i];
            s += v.x + v.y + v.z + v.w;
            sq += v.x * v.x + v.y * v.y + v.z * v.z + v.w * v.w;
        }
    }
    int lane = t & 63, wv = t >> 6;
    #pragma unroll
    for (int off = 32; off > 0; off >>= 1) {
        s += __shfl_down(s, off);
        sq += __shfl_down(sq, off);
    }
    __shared__ float red[8];
    if (lane == 0) { red[wv] = s; red[4 + wv] = sq; }
    __syncthreads();
    if (t == 0) {
        float S = red[0] + red[1] + red[2] + red[3];
        float Q = red[4] + red[5] + red[6] + red[7];
        float m = S / (float)NPIX_;
        float var = Q / (float)NPIX_ - m * m;
        float sc = g[c] * rsqrtf(var + EPSV);
        scsh[c] = sc;
        scsh[64 + c] = be[c] - m * sc;
    }
}

// ---------------------------------------------------------------------------
// offset conv3x3 on BN1+ReLU(A): BN applied during LDS staging.
// XCD-chunked swizzle (288 blocks, 36/XCD => 3 tile rows, 2.4MB < 4MB L2)
// ---------------------------------------------------------------------------
__global__ __launch_bounds__(256) void k_offconv(const float* __restrict__ A,
        const float* __restrict__ scsh1,
        const float* __restrict__ ow, const float* __restrict__ ob,
        float* __restrict__ off)
{
    __shared__ float As[16 * 18 * 18];   // [c][r][col]
    __shared__ float wsh[16 * 9 * 20];   // [c][tap][oc pad20]
    __shared__ float scb[64], shb[64];
    int t = threadIdx.x;
    int wg = blockIdx.x;
    int bid = (wg & 7) * 36 + (wg >> 3);   // XCD-chunked
    int b = bid / 144;
    int tile = bid % 144;
    int ty = tile / 12, tx = tile % 12;
    int y0 = ty * 16, x0 = tx * 16;
    int lx = t & 15, ly = t >> 4;

    if (t < 64) { scb[t] = scsh1[t]; shb[t] = scsh1[64 + t]; }

    float acc[18];
    #pragma unroll
    for (int i = 0; i < 18; ++i) acc[i] = 0.f;

    for (int cg = 0; cg < 4; ++cg) {
        int c0 = cg * 16;
        __syncthreads();
        for (int e = t; e < 16 * 18 * 18; e += 256) {
            int c = e / 324, rem = e % 324;
            int r = rem / 18, col = rem % 18;
            int gy = y0 - 1 + r, gx = x0 - 1 + col;
            float v = 0.f;
            if (gy >= 0 && gy < H_ && gx >= 0 && gx < W_) {
                float a = A[(b * 64 + c0 + c) * HW_ + gy * W_ + gx];
                v = fmaxf(fmaf(a, scb[c0 + c], shb[c0 + c]), 0.f);
            }
            As[e] = v;
        }
        for (int e = t; e < 16 * 9 * 18; e += 256) {
            int c = e / 162, rem = e % 162;
            int tap = rem / 18, oc = rem % 18;
            wsh[(c * 9 + tap) * 20 + oc] = ow[((oc * 64) + c0 + c) * 9 + tap];
        }
        __syncthreads();
        for (int c = 0; c < 16; ++c) {
            #pragma unroll
            for (int tap = 0; tap < 9; ++tap) {
                int ky = tap / 3, kx = tap % 3;
                float a = As[c * 324 + (ly + ky) * 18 + (lx + kx)];
                const float* wr = &wsh[(c * 9 + tap) * 20];
                #pragma unroll
                for (int oc = 0; oc < 18; ++oc)
                    acc[oc] = fmaf(a, wr[oc], acc[oc]);
            }
        }
    }
    #pragma unroll
    for (int oc = 0; oc < 18; ++oc)
        off[(b * 18 + oc) * HW_ + (y0 + ly) * W_ + x0 + lx] = acc[oc] + ob[oc];
}

// ---------------------------------------------------------------------------
// deformable conv, BN1+ReLU fused into the bilinear corner reads, conv1x1#2
// folded into weights, BN2 sum/sumsq accumulated in epilogue.
// XCD-chunked swizzle: 1152 blocks, 144/XCD = 48 contiguous rows (2.4MB L2 set)
// ---------------------------------------------------------------------------
__global__ __launch_bounds__(256) void k_deform(const float* __restrict__ A,
        const float* __restrict__ scsh1,
        const float* __restrict__ off, const float* __restrict__ wk,
        const float* __restrict__ beff, float* __restrict__ out,
        float* __restrict__ sums2)
{
    __shared__ __align__(16) float vs[64][64];   // [c][p]
    __shared__ __align__(16) float wsh[64][64];  // [c][o]
    int t = threadIdx.x;
    int wg = blockIdx.x;
    int nid = (wg & 7) * 144 + (wg >> 3);        // XCD-chunked
    int base = nid * 64;
    int b = base / HW_;
    int hw0 = base % HW_;
    int h = hw0 / W_;
    int w0 = hw0 % W_;

    int p = t & 63, cg = t >> 6;
    int l = t & 63, wv = t >> 6;
    int pg = l & 15, og = wv * 4 + (l >> 4);

    // BN1 scale/shift for this thread's 16 channels (held in registers)
    float sc_[16], sh_[16];
    #pragma unroll
    for (int i = 0; i < 16; ++i) {
        sc_[i] = scsh1[cg * 16 + i];
        sh_[i] = scsh1[64 + cg * 16 + i];
    }

    float acc[4][4];
    #pragma unroll
    for (int i = 0; i < 4; ++i)
        #pragma unroll
        for (int j = 0; j < 4; ++j) acc[i][j] = 0.f;

    for (int k = 0; k < 9; ++k) {
        __syncthreads();   // protect previous iteration's LDS reads
        #pragma unroll
        for (int i = 0; i < 16; ++i) {
            int e = t + i * 256;
            ((float*)wsh)[e] = wk[k * 4096 + e];
        }
        float dy = off[((b * 18) + 2 * k) * HW_ + hw0 + p];
        float dx = off[((b * 18) + 2 * k + 1) * HW_ + hw0 + p];
        float py = (float)(h + k / 3 - 1) + dy;
        float px = (float)(w0 + p + k % 3 - 1) + dx;
        float fly = floorf(py), flx = floorf(px);
        float fy = py - fly, fx = px - flx;
        int y0i = (int)fly, x0i = (int)flx;
        float w00 = (1.f - fy) * (1.f - fx);
        float w01 = (1.f - fy) * fx;
        float w10 = fy * (1.f - fx);
        float w11 = fy * fx;
        bool yv0 = (y0i >= 0) && (y0i < H_);
        bool yv1 = (y0i + 1 >= 0) && (y0i + 1 < H_);
        bool xv0 = (x0i >= 0) && (x0i < W_);
        bool xv1 = (x0i + 1 >= 0) && (x0i + 1 < W_);
        if (!(yv0 && xv0)) w00 = 0.f;
        if (!(yv0 && xv1)) w01 = 0.f;
        if (!(yv1 && xv0)) w10 = 0.f;
        if (!(yv1 && xv1)) w11 = 0.f;
        int yc0 = min(max(y0i, 0), H_ - 1), yc1 = min(max(y0i + 1, 0), H_ - 1);
        int xc0 = min(max(x0i, 0), W_ - 1), xc1 = min(max(x0i + 1, 0), W_ - 1);
        int i00 = yc0 * W_ + xc0, i01 = yc0 * W_ + xc1;
        int i10 = yc1 * W_ + xc0, i11 = yc1 * W_ + xc1;

        const float* Ab = &A[(b * 64 + cg * 16) * HW_];
        #pragma unroll
        for (int i = 0; i < 16; ++i) {
            float a00 = fmaxf(fmaf(Ab[i00], sc_[i], sh_[i]), 0.f);
            float a01 = fmaxf(fmaf(Ab[i01], sc_[i], sh_[i]), 0.f);
            float a10 = fmaxf(fmaf(Ab[i10], sc_[i], sh_[i]), 0.f);
            float a11 = fmaxf(fmaf(Ab[i11], sc_[i], sh_[i]), 0.f);
            vs[cg * 16 + i][p] = a00 * w00 + a01 * w01 + a10 * w10 + a11 * w11;
            Ab += HW_;
        }
        __syncthreads();
        #pragma unroll 8
        for (int c = 0; c < 64; ++c) {
            float va[4], wa[4];
            *(float4*)va = *(const float4*)&vs[c][pg * 4];
            *(float4*)wa = *(const float4*)&wsh[c][og * 4];
            #pragma unroll
            for (int i = 0; i < 4; ++i)
                #pragma unroll
                for (int j = 0; j < 4; ++j)
                    acc[i][j] = fmaf(va[i], wa[j], acc[i][j]);
        }
    }

    // epilogue: write pre-BN2 output + accumulate per-channel sum/sumsq
    #pragma unroll
    for (int j = 0; j < 4; ++j) {
        int oc = og * 4 + j;
        float bias = beff[oc];
        float v0 = acc[0][j] + bias, v1 = acc[1][j] + bias;
        float v2 = acc[2][j] + bias, v3 = acc[3][j] + bias;
        *(float4*)&out[(b * 64 + oc) * HW_ + hw0 + pg * 4] =
            make_float4(v0, v1, v2, v3);
        float s = v0 + v1 + v2 + v3;
        float q = v0 * v0 + v1 * v1 + v2 * v2 + v3 * v3;
        // reduce over the 16 lanes (pg) that share this oc
        #pragma unroll
        for (int m = 8; m > 0; m >>= 1) {
            s += __shfl_xor(s, m);
            q += __shfl_xor(q, m);
        }
        if (pg == 0) {
            atomicAdd(&sums2[oc], s);
            atomicAdd(&sums2[64 + oc], q);
        }
    }
}

// ---------------------------------------------------------------------------
// BN2 apply from accumulated sums (stats computed inline per thread)
// ---------------------------------------------------------------------------
__global__ void k_bn2(float* __restrict__ y, const float* __restrict__ sums,
                      const float* __restrict__ g, const float* __restrict__ be)
{
    int idx = blockIdx.x * 256 + threadIdx.x;         // float4 index
    int c = ((idx * 4) / HW_) & 63;
    float m = sums[c] * (1.f / (float)NPIX_);
    float var = sums[64 + c] * (1.f / (float)NPIX_) - m * m;
    float sc = g[c] * rsqrtf(var + EPSV);
    float sh = be[c] - m * sc;
    float4 v = ((float4*)y)[idx];
    v.x = fmaf(v.x, sc, sh);
    v.y = fmaf(v.y, sc, sh);
    v.z = fmaf(v.z, sc, sh);
    v.w = fmaf(v.w, sc, sh);
    ((float4*)y)[idx] = v;
}

// ---------------------------------------------------------------------------
extern "C" void kernel_launch(void* const* d_in, const int* in_sizes, int n_in,
                              void* d_out, int out_size, void* d_ws, size_t ws_size,
                              hipStream_t stream)
{
    const float* x   = (const float*)d_in[0];
    const float* w1  = (const float*)d_in[1];
    const float* b1  = (const float*)d_in[2];
    const float* g1  = (const float*)d_in[3];
    const float* be1 = (const float*)d_in[4];
    const float* ow  = (const float*)d_in[5];
    const float* ob  = (const float*)d_in[6];
    const float* dw  = (const float*)d_in[7];
    const float* db  = (const float*)d_in[8];
    const float* w2  = (const float*)d_in[9];
    const float* b2  = (const float*)d_in[10];
    const float* g2  = (const float*)d_in[11];
    const float* be2 = (const float*)d_in[12];
    float* out = (float*)d_out;

    float* ws    = (float*)d_ws;
    float* A     = ws;                       // raw conv1x1 output (pre-BN1)
    float* offb  = A + (size_t)NPIX_ * 64;
    float* w1t   = offb + (size_t)B_ * 18 * HW_;
    float* wk    = w1t + 4096;
    float* beff  = wk + 9 * 4096;
    float* scsh1 = beff + 64;                // 128
    float* sums2 = scsh1 + 128;              // 128 (sum, sumsq per oc)

    hipLaunchKernelGGL(k_fold, dim3(144), dim3(256), 0, stream,
                       w1, w2, dw, db, b2, w1t, wk, beff, sums2);
    hipLaunchKernelGGL(k_conv1x1, dim3(NPIX_ / 64), dim3(256), 0, stream,
                       x, w1t, b1, A);
    hipLaunchKernelGGL(k_stats, dim3(64), dim3(256), 0, stream, A, g1, be1, scsh1);
    hipLaunchKernelGGL(k_offconv, dim3(288), dim3(256), 0, stream,
                       A, scsh1, ow, ob, offb);
    hipLaunchKernelGGL(k_deform, dim3(NPIX_ / 64), dim3(256), 0, stream,
                       A, scsh1, offb, wk, beff, out, sums2);
    hipLaunchKernelGGL(k_bn2, dim3((NPIX_ * 64 / 4) / 256), dim3(256), 0, stream,
                       out, sums2, g2, be2);
}

// Round 3
// 358.841 us; speedup vs baseline: 1.1637x; 1.1637x over previous
//
#include <hip/hip_runtime.h>
#include <math.h>

#define H_ 192
#define W_ 192
#define HW_ (H_*W_)      // 36864
#define B_ 2
#define C_ 64
#define NPIX_ (B_*HW_)   // 73728
#define EPSV 1e-5f

// ---------------------------------------------------------------------------
// Fold: w1t[c][o] = w1[o][c];  wk[k][c][p] = sum_o w2[p,o]*dw[o,c,k];
//       beff[p]  = sum_o w2[p,o]*db[o] + b2[p]
// ---------------------------------------------------------------------------
__global__ void k_fold(const float* __restrict__ w1, const float* __restrict__ w2,
                       const float* __restrict__ dw, const float* __restrict__ db,
                       const float* __restrict__ b2,
                       float* __restrict__ w1t, float* __restrict__ wk,
                       float* __restrict__ beff)
{
    int tid = blockIdx.x * 256 + threadIdx.x;   // 0..36863
    if (tid < 9 * 64 * 64) {
        int k = tid >> 12;
        int r = tid & 4095;
        int c = r >> 6;
        int p = r & 63;
        float acc = 0.f;
        #pragma unroll 8
        for (int o = 0; o < 64; ++o)
            acc = fmaf(w2[p * 64 + o], dw[(o * 64 + c) * 9 + k], acc);
        wk[tid] = acc;
    }
    if (tid < 4096) {
        int c = tid >> 6, o = tid & 63;
        w1t[c * 64 + o] = w1[o * 64 + c];
    }
    if (tid < 64) {
        float acc = b2[tid];
        #pragma unroll 8
        for (int o = 0; o < 64; ++o) acc = fmaf(w2[tid * 64 + o], db[o], acc);
        beff[tid] = acc;
    }
}

// ---------------------------------------------------------------------------
// conv1x1 #1: y[b,o,hw] = sum_c x[b,c,hw]*w1t[c][o] + b1[o]  (raw, pre-BN)
// ---------------------------------------------------------------------------
__global__ __launch_bounds__(256) void k_conv1x1(const float* __restrict__ x,
        const float* __restrict__ w1t, const float* __restrict__ b1,
        float* __restrict__ y)
{
    __shared__ __align__(16) float xs[64][64];   // [c][p]
    __shared__ __align__(16) float wsh[64][64];  // [c][o]
    int t = threadIdx.x;
    int base = blockIdx.x * 64;
    int b = base / HW_;
    int hw0 = base % HW_;

    #pragma unroll
    for (int i = 0; i < 16; ++i) {
        int e = t + i * 256;
        ((float*)wsh)[e] = w1t[e];
    }
    int p = t & 63, cg = t >> 6;
    #pragma unroll
    for (int i = 0; i < 16; ++i) {
        int c = cg * 16 + i;
        xs[c][p] = x[(b * 64 + c) * HW_ + hw0 + p];
    }
    __syncthreads();

    int l = t & 63, wv = t >> 6;
    int pg = l & 15;
    int og = wv * 4 + (l >> 4);
    float acc[4][4];
    #pragma unroll
    for (int i = 0; i < 4; ++i)
        #pragma unroll
        for (int j = 0; j < 4; ++j) acc[i][j] = 0.f;

    #pragma unroll 8
    for (int c = 0; c < 64; ++c) {
        float va[4], wa[4];
        *(float4*)va = *(const float4*)&xs[c][pg * 4];
        *(float4*)wa = *(const float4*)&wsh[c][og * 4];
        #pragma unroll
        for (int i = 0; i < 4; ++i)
            #pragma unroll
            for (int j = 0; j < 4; ++j)
                acc[i][j] = fmaf(va[i], wa[j], acc[i][j]);
    }

    #pragma unroll
    for (int j = 0; j < 4; ++j) {
        int oc = og * 4 + j;
        float bias = b1[oc];
        float4 o4 = make_float4(acc[0][j] + bias, acc[1][j] + bias,
                                acc[2][j] + bias, acc[3][j] + bias);
        *(float4*)&y[(b * 64 + oc) * HW_ + hw0 + pg * 4] = o4;
    }
}

// ---------------------------------------------------------------------------
// BN stats: one block per channel; writes scale, shift
// ---------------------------------------------------------------------------
__global__ void k_stats(const float* __restrict__ y, const float* __restrict__ g,
                        const float* __restrict__ be, float* __restrict__ scsh)
{
    int c = blockIdx.x;
    int t = threadIdx.x;
    float s = 0.f, sq = 0.f;
    for (int b = 0; b < B_; ++b) {
        const float4* p4 = (const float4*)&y[(b * 64 + c) * HW_];
        for (int i = t; i < HW_ / 4; i += 256) {
            float4 v = p4[i];
            s += v.x + v.y + v.z + v.w;
            sq += v.x * v.x + v.y * v.y + v.z * v.z + v.w * v.w;
        }
    }
    int lane = t & 63, wv = t >> 6;
    #pragma unroll
    for (int off = 32; off > 0; off >>= 1) {
        s += __shfl_down(s, off);
        sq += __shfl_down(sq, off);
    }
    __shared__ float red[8];
    if (lane == 0) { red[wv] = s; red[4 + wv] = sq; }
    __syncthreads();
    if (t == 0) {
        float S = red[0] + red[1] + red[2] + red[3];
        float Q = red[4] + red[5] + red[6] + red[7];
        float m = S / (float)NPIX_;
        float var = Q / (float)NPIX_ - m * m;
        float sc = g[c] * rsqrtf(var + EPSV);
        scsh[c] = sc;
        scsh[64 + c] = be[c] - m * sc;
    }
}

// ---------------------------------------------------------------------------
// BN apply (optional ReLU), in place, float4
// ---------------------------------------------------------------------------
__global__ void k_bn(float* __restrict__ y, const float* __restrict__ scsh, int relu)
{
    int idx = blockIdx.x * 256 + threadIdx.x;         // float4 index
    int c = ((idx * 4) / HW_) & 63;
    float sc = scsh[c], sh = scsh[64 + c];
    float4 v = ((float4*)y)[idx];
    v.x = fmaf(v.x, sc, sh);
    v.y = fmaf(v.y, sc, sh);
    v.z = fmaf(v.z, sc, sh);
    v.w = fmaf(v.w, sc, sh);
    if (relu) {
        v.x = fmaxf(v.x, 0.f); v.y = fmaxf(v.y, 0.f);
        v.z = fmaxf(v.z, 0.f); v.w = fmaxf(v.w, 0.f);
    }
    ((float4*)y)[idx] = v;
}

// ---------------------------------------------------------------------------
// offset conv3x3 on BN1+ReLU(A): BN applied during LDS staging.
// XCD-chunked swizzle (288 blocks, 36/XCD => 3 tile rows, 2.4MB < 4MB L2)
// ---------------------------------------------------------------------------
__global__ __launch_bounds__(256) void k_offconv(const float* __restrict__ A,
        const float* __restrict__ scsh1,
        const float* __restrict__ ow, const float* __restrict__ ob,
        float* __restrict__ off)
{
    __shared__ float As[16 * 18 * 18];   // [c][r][col]
    __shared__ float wsh[16 * 9 * 20];   // [c][tap][oc pad20]
    __shared__ float scb[64], shb[64];
    int t = threadIdx.x;
    int wg = blockIdx.x;
    int bid = (wg & 7) * 36 + (wg >> 3);   // XCD-chunked
    int b = bid / 144;
    int tile = bid % 144;
    int ty = tile / 12, tx = tile % 12;
    int y0 = ty * 16, x0 = tx * 16;
    int lx = t & 15, ly = t >> 4;

    if (t < 64) { scb[t] = scsh1[t]; shb[t] = scsh1[64 + t]; }

    float acc[18];
    #pragma unroll
    for (int i = 0; i < 18; ++i) acc[i] = 0.f;

    for (int cg = 0; cg < 4; ++cg) {
        int c0 = cg * 16;
        __syncthreads();
        for (int e = t; e < 16 * 18 * 18; e += 256) {
            int c = e / 324, rem = e % 324;
            int r = rem / 18, col = rem % 18;
            int gy = y0 - 1 + r, gx = x0 - 1 + col;
            float v = 0.f;
            if (gy >= 0 && gy < H_ && gx >= 0 && gx < W_) {
                float a = A[(b * 64 + c0 + c) * HW_ + gy * W_ + gx];
                v = fmaxf(fmaf(a, scb[c0 + c], shb[c0 + c]), 0.f);
            }
            As[e] = v;
        }
        for (int e = t; e < 16 * 9 * 18; e += 256) {
            int c = e / 162, rem = e % 162;
            int tap = rem / 18, oc = rem % 18;
            wsh[(c * 9 + tap) * 20 + oc] = ow[((oc * 64) + c0 + c) * 9 + tap];
        }
        __syncthreads();
        for (int c = 0; c < 16; ++c) {
            #pragma unroll
            for (int tap = 0; tap < 9; ++tap) {
                int ky = tap / 3, kx = tap % 3;
                float a = As[c * 324 + (ly + ky) * 18 + (lx + kx)];
                const float* wr = &wsh[(c * 9 + tap) * 20];
                #pragma unroll
                for (int oc = 0; oc < 18; ++oc)
                    acc[oc] = fmaf(a, wr[oc], acc[oc]);
            }
        }
    }
    #pragma unroll
    for (int oc = 0; oc < 18; ++oc)
        off[(b * 18 + oc) * HW_ + (y0 + ly) * W_ + x0 + lx] = acc[oc] + ob[oc];
}

// ---------------------------------------------------------------------------
// deformable conv, BN1+ReLU fused into the bilinear corner reads, conv1x1#2
// folded into weights. NO epilogue atomics (R2 regression suspect).
// XCD-chunked swizzle: 1152 blocks, 144/XCD = 48 contiguous rows (2.4MB L2 set)
// ---------------------------------------------------------------------------
__global__ __launch_bounds__(256) void k_deform(const float* __restrict__ A,
        const float* __restrict__ scsh1,
        const float* __restrict__ off, const float* __restrict__ wk,
        const float* __restrict__ beff, float* __restrict__ out)
{
    __shared__ __align__(16) float vs[64][64];   // [c][p]
    __shared__ __align__(16) float wsh[64][64];  // [c][o]
    int t = threadIdx.x;
    int wg = blockIdx.x;
    int nid = (wg & 7) * 144 + (wg >> 3);        // XCD-chunked
    int base = nid * 64;
    int b = base / HW_;
    int hw0 = base % HW_;
    int h = hw0 / W_;
    int w0 = hw0 % W_;

    int p = t & 63, cg = t >> 6;
    int l = t & 63, wv = t >> 6;
    int pg = l & 15, og = wv * 4 + (l >> 4);

    // BN1 scale/shift for this thread's 16 channels (held in registers)
    float sc_[16], sh_[16];
    #pragma unroll
    for (int i = 0; i < 16; ++i) {
        sc_[i] = scsh1[cg * 16 + i];
        sh_[i] = scsh1[64 + cg * 16 + i];
    }

    float acc[4][4];
    #pragma unroll
    for (int i = 0; i < 4; ++i)
        #pragma unroll
        for (int j = 0; j < 4; ++j) acc[i][j] = 0.f;

    for (int k = 0; k < 9; ++k) {
        __syncthreads();   // protect previous iteration's LDS reads
        #pragma unroll
        for (int i = 0; i < 16; ++i) {
            int e = t + i * 256;
            ((float*)wsh)[e] = wk[k * 4096 + e];
        }
        float dy = off[((b * 18) + 2 * k) * HW_ + hw0 + p];
        float dx = off[((b * 18) + 2 * k + 1) * HW_ + hw0 + p];
        float py = (float)(h + k / 3 - 1) + dy;
        float px = (float)(w0 + p + k % 3 - 1) + dx;
        float fly = floorf(py), flx = floorf(px);
        float fy = py - fly, fx = px - flx;
        int y0i = (int)fly, x0i = (int)flx;
        float w00 = (1.f - fy) * (1.f - fx);
        float w01 = (1.f - fy) * fx;
        float w10 = fy * (1.f - fx);
        float w11 = fy * fx;
        bool yv0 = (y0i >= 0) && (y0i < H_);
        bool yv1 = (y0i + 1 >= 0) && (y0i + 1 < H_);
        bool xv0 = (x0i >= 0) && (x0i < W_);
        bool xv1 = (x0i + 1 >= 0) && (x0i + 1 < W_);
        if (!(yv0 && xv0)) w00 = 0.f;
        if (!(yv0 && xv1)) w01 = 0.f;
        if (!(yv1 && xv0)) w10 = 0.f;
        if (!(yv1 && xv1)) w11 = 0.f;
        int yc0 = min(max(y0i, 0), H_ - 1), yc1 = min(max(y0i + 1, 0), H_ - 1);
        int xc0 = min(max(x0i, 0), W_ - 1), xc1 = min(max(x0i + 1, 0), W_ - 1);
        int i00 = yc0 * W_ + xc0, i01 = yc0 * W_ + xc1;
        int i10 = yc1 * W_ + xc0, i11 = yc1 * W_ + xc1;

        const float* Ab = &A[(b * 64 + cg * 16) * HW_];
        #pragma unroll
        for (int i = 0; i < 16; ++i) {
            float a00 = fmaxf(fmaf(Ab[i00], sc_[i], sh_[i]), 0.f);
            float a01 = fmaxf(fmaf(Ab[i01], sc_[i], sh_[i]), 0.f);
            float a10 = fmaxf(fmaf(Ab[i10], sc_[i], sh_[i]), 0.f);
            float a11 = fmaxf(fmaf(Ab[i11], sc_[i], sh_[i]), 0.f);
            vs[cg * 16 + i][p] = a00 * w00 + a01 * w01 + a10 * w10 + a11 * w11;
            Ab += HW_;
        }
        __syncthreads();
        #pragma unroll 8
        for (int c = 0; c < 64; ++c) {
            float va[4], wa[4];
            *(float4*)va = *(const float4*)&vs[c][pg * 4];
            *(float4*)wa = *(const float4*)&wsh[c][og * 4];
            #pragma unroll
            for (int i = 0; i < 4; ++i)
                #pragma unroll
                for (int j = 0; j < 4; ++j)
                    acc[i][j] = fmaf(va[i], wa[j], acc[i][j]);
        }
    }

    #pragma unroll
    for (int j = 0; j < 4; ++j) {
        int oc = og * 4 + j;
        float bias = beff[oc];
        float4 o4 = make_float4(acc[0][j] + bias, acc[1][j] + bias,
                                acc[2][j] + bias, acc[3][j] + bias);
        *(float4*)&out[(b * 64 + oc) * HW_ + hw0 + pg * 4] = o4;
    }
}

// ---------------------------------------------------------------------------
extern "C" void kernel_launch(void* const* d_in, const int* in_sizes, int n_in,
                              void* d_out, int out_size, void* d_ws, size_t ws_size,
                              hipStream_t stream)
{
    const float* x   = (const float*)d_in[0];
    const float* w1  = (const float*)d_in[1];
    const float* b1  = (const float*)d_in[2];
    const float* g1  = (const float*)d_in[3];
    const float* be1 = (const float*)d_in[4];
    const float* ow  = (const float*)d_in[5];
    const float* ob  = (const float*)d_in[6];
    const float* dw  = (const float*)d_in[7];
    const float* db  = (const float*)d_in[8];
    const float* w2  = (const float*)d_in[9];
    const float* b2  = (const float*)d_in[10];
    const float* g2  = (const float*)d_in[11];
    const float* be2 = (const float*)d_in[12];
    float* out = (float*)d_out;

    float* ws    = (float*)d_ws;
    float* A     = ws;                       // raw conv1x1 output (pre-BN1)
    float* offb  = A + (size_t)NPIX_ * 64;
    float* w1t   = offb + (size_t)B_ * 18 * HW_;
    float* wk    = w1t + 4096;
    float* beff  = wk + 9 * 4096;
    float* scsh1 = beff + 64;                // 128
    float* scsh2 = scsh1 + 128;              // 128

    hipLaunchKernelGGL(k_fold, dim3(144), dim3(256), 0, stream,
                       w1, w2, dw, db, b2, w1t, wk, beff);
    hipLaunchKernelGGL(k_conv1x1, dim3(NPIX_ / 64), dim3(256), 0, stream,
                       x, w1t, b1, A);
    hipLaunchKernelGGL(k_stats, dim3(64), dim3(256), 0, stream, A, g1, be1, scsh1);
    hipLaunchKernelGGL(k_offconv, dim3(288), dim3(256), 0, stream,
                       A, scsh1, ow, ob, offb);
    hipLaunchKernelGGL(k_deform, dim3(NPIX_ / 64), dim3(256), 0, stream,
                       A, scsh1, offb, wk, beff, out);
    hipLaunchKernelGGL(k_stats, dim3(64), dim3(256), 0, stream, out, g2, be2, scsh2);
    hipLaunchKernelGGL(k_bn, dim3((NPIX_ * 64 / 4) / 256), dim3(256), 0, stream,
                       out, scsh2, 0);
}

// Round 4
// 265.598 us; speedup vs baseline: 1.5723x; 1.3511x over previous
//
#include <hip/hip_runtime.h>
#include <math.h>

#define H_ 192
#define W_ 192
#define HW_ (H_*W_)      // 36864
#define B_ 2
#define C_ 64
#define NPIX_ (B_*HW_)   // 73728
#define EPSV 1e-5f

typedef short s8v  __attribute__((ext_vector_type(8)));
typedef float f4v  __attribute__((ext_vector_type(4)));

__device__ __forceinline__ unsigned short f2bf(float f) {
    union { float f; unsigned u; } x; x.f = f;
    unsigned r = x.u + 0x7fffu + ((x.u >> 16) & 1u);   // RNE
    return (unsigned short)(r >> 16);
}

// ---------------------------------------------------------------------------
// Fold: w1t[c][o] = w1[o][c];
//       wkT[k][p][c] = bf16( sum_o w2[p,o]*dw[o,c,k] )   (p=out-ch, c=in-ch)
//       beff[p] = sum_o w2[p,o]*db[o] + b2[p]
// ---------------------------------------------------------------------------
__global__ void k_fold(const float* __restrict__ w1, const float* __restrict__ w2,
                       const float* __restrict__ dw, const float* __restrict__ db,
                       const float* __restrict__ b2,
                       float* __restrict__ w1t, unsigned short* __restrict__ wkT,
                       float* __restrict__ beff)
{
    int tid = blockIdx.x * 256 + threadIdx.x;   // 0..36863
    if (tid < 9 * 64 * 64) {
        int k = tid >> 12;
        int r = tid & 4095;
        int c = r >> 6;
        int p = r & 63;
        float acc = 0.f;
        #pragma unroll 8
        for (int o = 0; o < 64; ++o)
            acc = fmaf(w2[p * 64 + o], dw[(o * 64 + c) * 9 + k], acc);
        wkT[(k << 12) + (p << 6) + c] = f2bf(acc);
    }
    if (tid < 4096) {
        int c = tid >> 6, o = tid & 63;
        w1t[c * 64 + o] = w1[o * 64 + c];
    }
    if (tid < 64) {
        float acc = b2[tid];
        #pragma unroll 8
        for (int o = 0; o < 64; ++o) acc = fmaf(w2[tid * 64 + o], db[o], acc);
        beff[tid] = acc;
    }
}

// ---------------------------------------------------------------------------
// conv1x1 #1 (fp32 VALU): y = x * w1t + b1  (raw, pre-BN)
// ---------------------------------------------------------------------------
__global__ __launch_bounds__(256) void k_conv1x1(const float* __restrict__ x,
        const float* __restrict__ w1t, const float* __restrict__ b1,
        float* __restrict__ y)
{
    __shared__ __align__(16) float xs[64][64];   // [c][p]
    __shared__ __align__(16) float wsh[64][64];  // [c][o]
    int t = threadIdx.x;
    int base = blockIdx.x * 64;
    int b = base / HW_;
    int hw0 = base % HW_;

    #pragma unroll
    for (int i = 0; i < 16; ++i) {
        int e = t + i * 256;
        ((float*)wsh)[e] = w1t[e];
    }
    int p = t & 63, cg = t >> 6;
    #pragma unroll
    for (int i = 0; i < 16; ++i) {
        int c = cg * 16 + i;
        xs[c][p] = x[(b * 64 + c) * HW_ + hw0 + p];
    }
    __syncthreads();

    int l = t & 63, wv = t >> 6;
    int pg = l & 15;
    int og = wv * 4 + (l >> 4);
    float acc[4][4];
    #pragma unroll
    for (int i = 0; i < 4; ++i)
        #pragma unroll
        for (int j = 0; j < 4; ++j) acc[i][j] = 0.f;

    #pragma unroll 8
    for (int c = 0; c < 64; ++c) {
        float va[4], wa[4];
        *(float4*)va = *(const float4*)&xs[c][pg * 4];
        *(float4*)wa = *(const float4*)&wsh[c][og * 4];
        #pragma unroll
        for (int i = 0; i < 4; ++i)
            #pragma unroll
            for (int j = 0; j < 4; ++j)
                acc[i][j] = fmaf(va[i], wa[j], acc[i][j]);
    }

    #pragma unroll
    for (int j = 0; j < 4; ++j) {
        int oc = og * 4 + j;
        float bias = b1[oc];
        float4 o4 = make_float4(acc[0][j] + bias, acc[1][j] + bias,
                                acc[2][j] + bias, acc[3][j] + bias);
        *(float4*)&y[(b * 64 + oc) * HW_ + hw0 + pg * 4] = o4;
    }
}

// ---------------------------------------------------------------------------
// BN stats: one block per channel; writes scale, shift
// ---------------------------------------------------------------------------
__global__ void k_stats(const float* __restrict__ y, const float* __restrict__ g,
                        const float* __restrict__ be, float* __restrict__ scsh)
{
    int c = blockIdx.x;
    int t = threadIdx.x;
    float s = 0.f, sq = 0.f;
    for (int b = 0; b < B_; ++b) {
        const float4* p4 = (const float4*)&y[(b * 64 + c) * HW_];
        for (int i = t; i < HW_ / 4; i += 256) {
            float4 v = p4[i];
            s += v.x + v.y + v.z + v.w;
            sq += v.x * v.x + v.y * v.y + v.z * v.z + v.w * v.w;
        }
    }
    int lane = t & 63, wv = t >> 6;
    #pragma unroll
    for (int off = 32; off > 0; off >>= 1) {
        s += __shfl_down(s, off);
        sq += __shfl_down(sq, off);
    }
    __shared__ float red[8];
    if (lane == 0) { red[wv] = s; red[4 + wv] = sq; }
    __syncthreads();
    if (t == 0) {
        float S = red[0] + red[1] + red[2] + red[3];
        float Q = red[4] + red[5] + red[6] + red[7];
        float m = S / (float)NPIX_;
        float var = Q / (float)NPIX_ - m * m;
        float sc = g[c] * rsqrtf(var + EPSV);
        scsh[c] = sc;
        scsh[64 + c] = be[c] - m * sc;
    }
}

// ---------------------------------------------------------------------------
// BN apply, in place, float4
// ---------------------------------------------------------------------------
__global__ void k_bn(float* __restrict__ y, const float* __restrict__ scsh, int relu)
{
    int idx = blockIdx.x * 256 + threadIdx.x;         // float4 index
    int c = ((idx * 4) / HW_) & 63;
    float sc = scsh[c], sh = scsh[64 + c];
    float4 v = ((float4*)y)[idx];
    v.x = fmaf(v.x, sc, sh);
    v.y = fmaf(v.y, sc, sh);
    v.z = fmaf(v.z, sc, sh);
    v.w = fmaf(v.w, sc, sh);
    if (relu) {
        v.x = fmaxf(v.x, 0.f); v.y = fmaxf(v.y, 0.f);
        v.z = fmaxf(v.z, 0.f); v.w = fmaxf(v.w, 0.f);
    }
    ((float4*)y)[idx] = v;
}

// ---------------------------------------------------------------------------
// offset conv3x3 on BN1+ReLU(A): BN applied during LDS staging.
// ---------------------------------------------------------------------------
__global__ __launch_bounds__(256) void k_offconv(const float* __restrict__ A,
        const float* __restrict__ scsh1,
        const float* __restrict__ ow, const float* __restrict__ ob,
        float* __restrict__ off)
{
    __shared__ float As[16 * 18 * 18];   // [c][r][col]
    __shared__ float wsh[16 * 9 * 20];   // [c][tap][oc pad20]
    __shared__ float scb[64], shb[64];
    int t = threadIdx.x;
    int wg = blockIdx.x;
    int bid = (wg & 7) * 36 + (wg >> 3);   // XCD-chunked
    int b = bid / 144;
    int tile = bid % 144;
    int ty = tile / 12, tx = tile % 12;
    int y0 = ty * 16, x0 = tx * 16;
    int lx = t & 15, ly = t >> 4;

    if (t < 64) { scb[t] = scsh1[t]; shb[t] = scsh1[64 + t]; }

    float acc[18];
    #pragma unroll
    for (int i = 0; i < 18; ++i) acc[i] = 0.f;

    for (int cg = 0; cg < 4; ++cg) {
        int c0 = cg * 16;
        __syncthreads();
        for (int e = t; e < 16 * 18 * 18; e += 256) {
            int c = e / 324, rem = e % 324;
            int r = rem / 18, col = rem % 18;
            int gy = y0 - 1 + r, gx = x0 - 1 + col;
            float v = 0.f;
            if (gy >= 0 && gy < H_ && gx >= 0 && gx < W_) {
                float a = A[(b * 64 + c0 + c) * HW_ + gy * W_ + gx];
                v = fmaxf(fmaf(a, scb[c0 + c], shb[c0 + c]), 0.f);
            }
            As[e] = v;
        }
        for (int e = t; e < 16 * 9 * 18; e += 256) {
            int c = e / 162, rem = e % 162;
            int tap = rem / 18, oc = rem % 18;
            wsh[(c * 9 + tap) * 20 + oc] = ow[((oc * 64) + c0 + c) * 9 + tap];
        }
        __syncthreads();
        for (int c = 0; c < 16; ++c) {
            #pragma unroll
            for (int tap = 0; tap < 9; ++tap) {
                int ky = tap / 3, kx = tap % 3;
                float a = As[c * 324 + (ly + ky) * 18 + (lx + kx)];
                const float* wr = &wsh[(c * 9 + tap) * 20];
                #pragma unroll
                for (int oc = 0; oc < 18; ++oc)
                    acc[oc] = fmaf(a, wr[oc], acc[oc]);
            }
        }
    }
    #pragma unroll
    for (int oc = 0; oc < 18; ++oc)
        off[(b * 18 + oc) * HW_ + (y0 + ly) * W_ + x0 + lx] = acc[oc] + ob[oc];
}

// ---------------------------------------------------------------------------
// deformable conv via bf16 MFMA. Per block: 64px x 64oc tile, K = 9 taps x 64ch.
// Per tap: gather V[64px][64ch] (BN1+ReLU fused) -> bf16 XOR-swizzled LDS;
// stage W[64oc][64ch] bf16 (pre-transposed wkT); 4 waves x 8 mfma_16x16x32_bf16.
// LDS granule swizzle: 16B granule index g at row r lives at (g ^ (r&7)).
// ---------------------------------------------------------------------------
__global__ __launch_bounds__(256) void k_deform(const float* __restrict__ A,
        const float* __restrict__ scsh1, const float* __restrict__ off,
        const unsigned short* __restrict__ wkT, const float* __restrict__ beff,
        float* __restrict__ out)
{
    __shared__ __align__(16) unsigned short Vt[64 * 64];  // [px][ch] swizzled
    __shared__ __align__(16) unsigned short Wt[64 * 64];  // [oc][ch] swizzled
    __shared__ float scb[64], shb[64], bb[64];

    int t = threadIdx.x;
    int wg = blockIdx.x;
    int nid = (wg & 7) * 144 + (wg >> 3);        // XCD-chunked
    int base = nid * 64;
    int b = base / HW_;
    int hw0 = base % HW_;
    int h = hw0 / W_;
    int w0 = hw0 % W_;

    if (t < 64) { scb[t] = scsh1[t]; shb[t] = scsh1[64 + t]; bb[t] = beff[t]; }

    int p  = t & 63;          // gather: pixel owned by this thread
    int cg = t >> 6;          // gather: 16-channel group (uniform per wave)
    int lane = t & 63, wv = t >> 6;
    int m = lane & 15, kq = lane >> 4;           // MFMA lane decomposition

    f4v acc[4];
    #pragma unroll
    for (int n = 0; n < 4; ++n) acc[n] = (f4v){0.f, 0.f, 0.f, 0.f};

    for (int k = 0; k < 9; ++k) {
        __syncthreads();   // previous tap's LDS reads complete

        // ---- stage Wt: 512 granules of 16B, thread t copies granules 2t,2t+1
        {
            const int4* src = (const int4*)(wkT + ((size_t)k << 12));
            int g0 = t * 2;
            int r0 = g0 >> 3;
            *(int4*)&Wt[(r0 << 6) + (((g0 & 7) ^ (r0 & 7)) << 3)] = src[g0];
            int g1 = g0 + 1;
            *(int4*)&Wt[(r0 << 6) + (((g1 & 7) ^ (r0 & 7)) << 3)] = src[g1];
        }

        // ---- bilinear gather (BN1+ReLU fused), 16 channels for pixel p
        float dy = off[((b * 18) + 2 * k) * HW_ + hw0 + p];
        float dx = off[((b * 18) + 2 * k + 1) * HW_ + hw0 + p];
        float py = (float)(h + k / 3 - 1) + dy;
        float px = (float)(w0 + p + k % 3 - 1) + dx;
        float fly = floorf(py), flx = floorf(px);
        float fy = py - fly, fx = px - flx;
        int y0i = (int)fly, x0i = (int)flx;
        float w00 = (1.f - fy) * (1.f - fx);
        float w01 = (1.f - fy) * fx;
        float w10 = fy * (1.f - fx);
        float w11 = fy * fx;
        bool yv0 = (y0i >= 0) && (y0i < H_);
        bool yv1 = (y0i + 1 >= 0) && (y0i + 1 < H_);
        bool xv0 = (x0i >= 0) && (x0i < W_);
        bool xv1 = (x0i + 1 >= 0) && (x0i + 1 < W_);
        if (!(yv0 && xv0)) w00 = 0.f;
        if (!(yv0 && xv1)) w01 = 0.f;
        if (!(yv1 && xv0)) w10 = 0.f;
        if (!(yv1 && xv1)) w11 = 0.f;
        int yc0 = min(max(y0i, 0), H_ - 1), yc1 = min(max(y0i + 1, 0), H_ - 1);
        int xc0 = min(max(x0i, 0), W_ - 1), xc1 = min(max(x0i + 1, 0), W_ - 1);
        int i00 = yc0 * W_ + xc0, i01 = yc0 * W_ + xc1;
        int i10 = yc1 * W_ + xc0, i11 = yc1 * W_ + xc1;

        const float* Ab = &A[(b * 64 + cg * 16) * HW_];
        unsigned pw[8];
        #pragma unroll
        for (int i = 0; i < 8; ++i) {
            unsigned v2 = 0;
            #pragma unroll
            for (int j = 0; j < 2; ++j) {
                int c = 2 * i + j;
                float sc = scb[cg * 16 + c], sh = shb[cg * 16 + c];
                const float* Ac = Ab + (size_t)c * HW_;
                float a00 = fmaxf(fmaf(Ac[i00], sc, sh), 0.f);
                float a01 = fmaxf(fmaf(Ac[i01], sc, sh), 0.f);
                float a10 = fmaxf(fmaf(Ac[i10], sc, sh), 0.f);
                float a11 = fmaxf(fmaf(Ac[i11], sc, sh), 0.f);
                float v = a00 * w00 + a01 * w01 + a10 * w10 + a11 * w11;
                v2 |= ((unsigned)f2bf(v)) << (16 * j);
            }
            pw[i] = v2;
        }
        {
            int g0 = cg * 2;                 // ch granule for c0..c0+7
            int4 lo = make_int4((int)pw[0], (int)pw[1], (int)pw[2], (int)pw[3]);
            int4 hi = make_int4((int)pw[4], (int)pw[5], (int)pw[6], (int)pw[7]);
            *(int4*)&Vt[(p << 6) + ((g0 ^ (p & 7)) << 3)] = lo;
            *(int4*)&Vt[(p << 6) + (((g0 + 1) ^ (p & 7)) << 3)] = hi;
        }
        __syncthreads();

        // ---- MFMA: wave wv owns px rows [wv*16, wv*16+16), all 64 oc
        int rowA = wv * 16 + m;
        s8v a0 = *(const s8v*)&Vt[(rowA << 6) + (((0 + kq) ^ (rowA & 7)) << 3)];
        s8v a1 = *(const s8v*)&Vt[(rowA << 6) + (((4 + kq) ^ (rowA & 7)) << 3)];
        #pragma unroll
        for (int n = 0; n < 4; ++n) {
            int rowB = n * 16 + m;
            s8v b0 = *(const s8v*)&Wt[(rowB << 6) + (((0 + kq) ^ (rowB & 7)) << 3)];
            s8v b1 = *(const s8v*)&Wt[(rowB << 6) + (((4 + kq) ^ (rowB & 7)) << 3)];
            acc[n] = __builtin_amdgcn_mfma_f32_16x16x32_bf16(a0, b0, acc[n], 0, 0, 0);
            acc[n] = __builtin_amdgcn_mfma_f32_16x16x32_bf16(a1, b1, acc[n], 0, 0, 0);
        }
    }

    // ---- epilogue: C/D layout col=lane&15 (oc), row=(lane>>4)*4+reg (px)
    #pragma unroll
    for (int n = 0; n < 4; ++n) {
        int oc = n * 16 + m;
        float bias = bb[oc];
        #pragma unroll
        for (int r = 0; r < 4; ++r) {
            int pxr = wv * 16 + kq * 4 + r;
            out[(b * 64 + oc) * HW_ + hw0 + pxr] = acc[n][r] + bias;
        }
    }
}

// ---------------------------------------------------------------------------
extern "C" void kernel_launch(void* const* d_in, const int* in_sizes, int n_in,
                              void* d_out, int out_size, void* d_ws, size_t ws_size,
                              hipStream_t stream)
{
    const float* x   = (const float*)d_in[0];
    const float* w1  = (const float*)d_in[1];
    const float* b1  = (const float*)d_in[2];
    const float* g1  = (const float*)d_in[3];
    const float* be1 = (const float*)d_in[4];
    const float* ow  = (const float*)d_in[5];
    const float* ob  = (const float*)d_in[6];
    const float* dw  = (const float*)d_in[7];
    const float* db  = (const float*)d_in[8];
    const float* w2  = (const float*)d_in[9];
    const float* b2  = (const float*)d_in[10];
    const float* g2  = (const float*)d_in[11];
    const float* be2 = (const float*)d_in[12];
    float* out = (float*)d_out;

    float* ws    = (float*)d_ws;
    float* A     = ws;                           // raw conv1x1 output (pre-BN1)
    float* offb  = A + (size_t)NPIX_ * 64;
    float* w1t   = offb + (size_t)B_ * 18 * HW_;
    unsigned short* wkT = (unsigned short*)(w1t + 4096);   // 9*4096 bf16
    float* beff  = (float*)(wkT + 9 * 4096);     // 64
    float* scsh1 = beff + 64;                    // 128
    float* scsh2 = scsh1 + 128;                  // 128

    hipLaunchKernelGGL(k_fold, dim3(144), dim3(256), 0, stream,
                       w1, w2, dw, db, b2, w1t, wkT, beff);
    hipLaunchKernelGGL(k_conv1x1, dim3(NPIX_ / 64), dim3(256), 0, stream,
                       x, w1t, b1, A);
    hipLaunchKernelGGL(k_stats, dim3(64), dim3(256), 0, stream, A, g1, be1, scsh1);
    hipLaunchKernelGGL(k_offconv, dim3(288), dim3(256), 0, stream,
                       A, scsh1, ow, ob, offb);
    hipLaunchKernelGGL(k_deform, dim3(NPIX_ / 64), dim3(256), 0, stream,
                       A, scsh1, offb, wkT, beff, out);
    hipLaunchKernelGGL(k_stats, dim3(64), dim3(256), 0, stream, out, g2, be2, scsh2);
    hipLaunchKernelGGL(k_bn, dim3((NPIX_ * 64 / 4) / 256), dim3(256), 0, stream,
                       out, scsh2, 0);
}